// Round 2
// baseline (309.449 us; speedup 1.0000x reference)
//
#include <hip/hip_runtime.h>

// GenerateNodes: out[n,t,o,k] = sum_c mix[n,t,c] * W[k,o,c] + b[k,o]
// mix = concat(x [16384,3200], seeds [16384,15])  -> GEMM M=16384, K=3215, Ncol=60
// R1: bf16 MFMA, A direct-from-global, B prepacked in d_ws. 1 wave/SIMD -> latency-bound.
// R2: K-split x4 (4 waves/SIMD), fp32 partials in d_ws, tiny reduce kernel adds bias.

#define NROWS    16384
#define CIN      3200
#define SEED_K   15
#define LIN_IN   3215
#define NCOL     60
#define KB_MAIN  100          // 3200 / 32
#define KB_TOT   101          // + tail block covering the 15 seed channels
#define WB_ELEMS (KB_TOT * 4 * 64 * 8)   // 206848 ushorts = 413696 B
#define NSPLIT   4
#define KB_PER_SPLIT 25
#define PART_OFF 524288       // byte offset of partials in d_ws (512 KB, past Wb)

typedef __attribute__((ext_vector_type(8))) __bf16 bf16x8;
typedef __attribute__((ext_vector_type(4))) float f32x4;
typedef __attribute__((ext_vector_type(8))) unsigned short ushort8;

__device__ inline unsigned short f2bf_rne(float f) {
    unsigned int u = __builtin_bit_cast(unsigned int, f);
    u += 0x7fffu + ((u >> 16) & 1u);
    return (unsigned short)(u >> 16);
}

__device__ inline bf16x8 to_bf16x8(f32x4 a0, f32x4 a1) {
    ushort8 u;
    u[0] = f2bf_rne(a0[0]); u[1] = f2bf_rne(a0[1]);
    u[2] = f2bf_rne(a0[2]); u[3] = f2bf_rne(a0[3]);
    u[4] = f2bf_rne(a1[0]); u[5] = f2bf_rne(a1[1]);
    u[6] = f2bf_rne(a1[2]); u[7] = f2bf_rne(a1[3]);
    return __builtin_bit_cast(bf16x8, u);
}

// Pack W[20,3,3215] fp32 into bf16 B-fragment order:
// Wb[kb][nt][lane][jj] = B[k = kb*32 + (lane>>4)*8 + jj][n = nt*16 + (lane&15)]
// where B[c][j] = W[j%20][j/20][c]; zero-pad k>=3215 and n>=60.
__global__ void prep_B(const float* __restrict__ W, unsigned short* __restrict__ Wb) {
    int idx = blockIdx.x * blockDim.x + threadIdx.x;
    if (idx >= WB_ELEMS) return;
    int jj   = idx & 7;
    int lane = (idx >> 3) & 63;
    int nt   = (idx >> 9) & 3;
    int kb   = idx >> 11;
    int k = kb * 32 + (lane >> 4) * 8 + jj;
    int n = nt * 16 + (lane & 15);
    float v = 0.0f;
    if (k < LIN_IN && n < NCOL) {
        int o = n / 20, kn = n % 20;
        v = W[(kn * 3 + o) * LIN_IN + k];
    }
    Wb[idx] = f2bf_rne(v);
}

// Grid: NSPLIT * 256 blocks, 256 threads (4 waves). Block b: split = b>>8,
// row-block = b&255 (64 rows). Each wave: 16 rows x 64 cols over 25 k-blocks,
// partial tile -> part[split][16384 rows][64 cols] fp32 in d_ws.
__global__ __launch_bounds__(256) void gen_nodes_gemm(
    const float* __restrict__ x, const float* __restrict__ seeds,
    const unsigned short* __restrict__ Wb, float* __restrict__ part) {
    const int lane = threadIdx.x & 63;
    const int wave = threadIdx.x >> 6;
    const int quad = lane >> 4;
    const int l15  = lane & 15;
    const int split = blockIdx.x >> 8;
    const int row_base = (blockIdx.x & 255) * 64 + wave * 16;
    const int arow = row_base + l15;          // A-operand row for this lane

    const int kb0 = split * KB_PER_SPLIT;
    const float* xrow = x + (size_t)arow * CIN + quad * 8 + kb0 * 32;
    const unsigned short* wb0 = Wb + (size_t)kb0 * 2048 + lane * 8;

    f32x4 acc[4];
#pragma unroll
    for (int i = 0; i < 4; ++i) acc[i] = (f32x4){0.f, 0.f, 0.f, 0.f};

#pragma unroll 5
    for (int kb = 0; kb < KB_PER_SPLIT; ++kb) {
        const f32x4* ap = (const f32x4*)(xrow + kb * 32);
        f32x4 a0 = ap[0];
        f32x4 a1 = ap[1];
        const unsigned short* bb = wb0 + (size_t)kb * 2048;
        bf16x8 b0 = *(const bf16x8*)(bb);
        bf16x8 b1 = *(const bf16x8*)(bb + 512);
        bf16x8 b2 = *(const bf16x8*)(bb + 1024);
        bf16x8 b3 = *(const bf16x8*)(bb + 1536);
        bf16x8 af = to_bf16x8(a0, a1);
        acc[0] = __builtin_amdgcn_mfma_f32_16x16x32_bf16(af, b0, acc[0], 0, 0, 0);
        acc[1] = __builtin_amdgcn_mfma_f32_16x16x32_bf16(af, b1, acc[1], 0, 0, 0);
        acc[2] = __builtin_amdgcn_mfma_f32_16x16x32_bf16(af, b2, acc[2], 0, 0, 0);
        acc[3] = __builtin_amdgcn_mfma_f32_16x16x32_bf16(af, b3, acc[3], 0, 0, 0);
    }

    if (split == NSPLIT - 1) {
        // Tail: the 15 seed channels (k = 3200..3214), zero-padded to 32.
        const float* srow = seeds + (size_t)arow * SEED_K;
        f32x4 s0 = {0.f, 0.f, 0.f, 0.f}, s1 = {0.f, 0.f, 0.f, 0.f};
#pragma unroll
        for (int j = 0; j < 4; ++j) {
            int c = quad * 8 + j;
            if (c < SEED_K) s0[j] = srow[c];
            if (c + 4 < SEED_K) s1[j] = srow[c + 4];
        }
        bf16x8 af = to_bf16x8(s0, s1);
        const unsigned short* bb = Wb + (size_t)KB_MAIN * 2048 + lane * 8;
        bf16x8 b0 = *(const bf16x8*)(bb);
        bf16x8 b1 = *(const bf16x8*)(bb + 512);
        bf16x8 b2 = *(const bf16x8*)(bb + 1024);
        bf16x8 b3 = *(const bf16x8*)(bb + 1536);
        acc[0] = __builtin_amdgcn_mfma_f32_16x16x32_bf16(af, b0, acc[0], 0, 0, 0);
        acc[1] = __builtin_amdgcn_mfma_f32_16x16x32_bf16(af, b1, acc[1], 0, 0, 0);
        acc[2] = __builtin_amdgcn_mfma_f32_16x16x32_bf16(af, b2, acc[2], 0, 0, 0);
        acc[3] = __builtin_amdgcn_mfma_f32_16x16x32_bf16(af, b3, acc[3], 0, 0, 0);
    }

    // Partial store: C/D layout col = l15 + nt*16, row = quad*4 + r.
    float* pw = part + ((size_t)split * NROWS + row_base) * 64;
#pragma unroll
    for (int nt = 0; nt < 4; ++nt) {
#pragma unroll
        for (int r = 0; r < 4; ++r) {
            pw[(size_t)(quad * 4 + r) * 64 + nt * 16 + l15] = acc[nt][r];
        }
    }
}

// Sum the NSPLIT partials, add bias, write out [16384, 60].
__global__ __launch_bounds__(256) void reduce_out(
    const float* __restrict__ part, const float* __restrict__ b,
    float* __restrict__ out) {
    int idx = blockIdx.x * blockDim.x + threadIdx.x;   // 16384*64 threads
    int c = idx & 63;
    int m = idx >> 6;
    if (c >= NCOL) return;
    float s = b[(c % 20) * 3 + (c / 20)];
#pragma unroll
    for (int sp = 0; sp < NSPLIT; ++sp)
        s += part[((size_t)sp * NROWS + m) * 64 + c];
    out[(size_t)m * NCOL + c] = s;
}

extern "C" void kernel_launch(void* const* d_in, const int* in_sizes, int n_in,
                              void* d_out, int out_size, void* d_ws, size_t ws_size,
                              hipStream_t stream) {
    const float* x     = (const float*)d_in[0];
    const float* seeds = (const float*)d_in[1];
    const float* W     = (const float*)d_in[2];
    const float* b     = (const float*)d_in[3];
    float* out = (float*)d_out;
    unsigned short* Wb = (unsigned short*)d_ws;
    float* part = (float*)((char*)d_ws + PART_OFF);

    prep_B<<<(WB_ELEMS + 255) / 256, 256, 0, stream>>>(W, Wb);
    gen_nodes_gemm<<<NSPLIT * 256, 256, 0, stream>>>(x, seeds, Wb, part);
    reduce_out<<<NROWS * 64 / 256, 256, 0, stream>>>(part, b, out);
}